// Round 1
// baseline (54.536 us; speedup 1.0000x reference)
//
#include <hip/hip_runtime.h>

#define NNODE 62
#define NN (NNODE*NNODE)
#define FIN 5
#define HID 400
#define NTRIL 1953   // 62*63/2

// Kernel A: build M = (D^-1/2 W D^-1/2)^2 from lower-tri edge weights.
// Single block, tiny (62^3 fma). Writes 62x62 fp32 to d_ws.
__global__ __launch_bounds__(256) void build_M(const float* __restrict__ ew,
                                               const int* __restrict__ tx,
                                               const int* __restrict__ ty,
                                               float* __restrict__ M) {
    __shared__ float W[NN];
    __shared__ float dinv[NNODE];
    const int t = threadIdx.x;

    for (int i = t; i < NN; i += 256) W[i] = 0.f;
    __syncthreads();

    // set symmetric entries (diagonal written twice with same value — fine)
    for (int e = t; e < NTRIL; e += 256) {
        const int x = tx[e], y = ty[e];
        const float v = ew[e];
        W[x*NNODE + y] = v;
        W[y*NNODE + x] = v;
    }
    __syncthreads();

    // deg over rows (matches scatter over src), D^-1/2
    if (t < NNODE) {
        float s = 0.f;
        for (int j = 0; j < NNODE; ++j) s += fabsf(W[t*NNODE + j]);
        dinv[t] = (s > 0.f) ? (1.0f / sqrtf(s)) : 0.f;
    }
    __syncthreads();

    // normalize in place (element-wise, no cross deps)
    for (int i = t; i < NN; i += 256) {
        const int r = i / NNODE, c = i - r*NNODE;
        W[i] = dinv[r] * W[i] * dinv[c];
    }
    __syncthreads();

    // M = Wn @ Wn (symmetric, so transpose ambiguity is moot)
    for (int i = t; i < NN; i += 256) {
        const int r = i / NNODE, c = i - r*NNODE;
        float s = 0.f;
        for (int k = 0; k < NNODE; ++k) s += W[r*NNODE + k] * W[k*NNODE + c];
        M[i] = s;
    }
}

// Kernel B: one block per graph.
//   Y = M @ X[b]            (62x5, in LDS)
//   h = relu(Y @ lin_w + b) -> pooled = sum_n h  (each thread owns 1-2 cols)
//   out[b] = pooled @ fc_w + fc_b  (block reduce of 2 floats)
__global__ __launch_bounds__(256) void rgnn_fwd(const float* __restrict__ X,
                                                const float* __restrict__ M,
                                                const float* __restrict__ lin_w,
                                                const float* __restrict__ lin_b,
                                                const float* __restrict__ fc_w,
                                                const float* __restrict__ fc_b,
                                                float* __restrict__ out) {
    const int b = blockIdx.x;
    const int t = threadIdx.x;
    __shared__ float Xs[NNODE*FIN];
    __shared__ float Ys[NNODE*FIN];
    __shared__ float r0[256];
    __shared__ float r1[256];

    const float* xb = X + (size_t)b * (NNODE*FIN);
    for (int i = t; i < NNODE*FIN; i += 256) Xs[i] = xb[i];
    __syncthreads();

    // Y[n,f] = sum_i M[n,i] * X[i,f]
    for (int idx = t; idx < NNODE*FIN; idx += 256) {
        const int n = idx / FIN, f = idx - n*FIN;
        const float* Mr = M + n*NNODE;
        float s = 0.f;
        for (int i = 0; i < NNODE; ++i) s += Mr[i] * Xs[i*FIN + f];
        Ys[idx] = s;
    }
    __syncthreads();

    // column phase: thread t owns hidden cols {t, t+256 (if <400)}
    const int c0 = t;
    const int c1 = t + 256;
    const bool has1 = (c1 < HID);

    float lw0[FIN], lw1[FIN];
    #pragma unroll
    for (int f = 0; f < FIN; ++f) {
        lw0[f] = lin_w[f*HID + c0];
        lw1[f] = has1 ? lin_w[f*HID + c1] : 0.f;
    }
    const float lb0 = lin_b[c0];
    const float lb1 = has1 ? lin_b[c1] : 0.f;

    float acc0 = 0.f, acc1 = 0.f;
    #pragma unroll 2
    for (int n = 0; n < NNODE; ++n) {
        const float* y = Ys + n*FIN;   // broadcast read — conflict-free
        float z0 = lb0, z1 = lb1;
        #pragma unroll
        for (int f = 0; f < FIN; ++f) {
            z0 = fmaf(y[f], lw0[f], z0);
            z1 = fmaf(y[f], lw1[f], z1);
        }
        acc0 += fmaxf(z0, 0.f);
        acc1 += fmaxf(z1, 0.f);
    }

    float o0 = acc0 * fc_w[c0*2 + 0];
    float o1 = acc0 * fc_w[c0*2 + 1];
    if (has1) {
        o0 = fmaf(acc1, fc_w[c1*2 + 0], o0);
        o1 = fmaf(acc1, fc_w[c1*2 + 1], o1);
    }
    r0[t] = o0;
    r1[t] = o1;
    __syncthreads();
    #pragma unroll
    for (int s = 128; s > 0; s >>= 1) {
        if (t < s) { r0[t] += r0[t+s]; r1[t] += r1[t+s]; }
        __syncthreads();
    }
    if (t == 0) {
        out[b*2 + 0] = r0[0] + fc_b[0];
        out[b*2 + 1] = r1[0] + fc_b[1];
    }
}

extern "C" void kernel_launch(void* const* d_in, const int* in_sizes, int n_in,
                              void* d_out, int out_size, void* d_ws, size_t ws_size,
                              hipStream_t stream) {
    const float* X      = (const float*)d_in[0];
    const float* ew     = (const float*)d_in[2];
    const float* lin_w  = (const float*)d_in[3];
    const float* lin_b  = (const float*)d_in[4];
    const float* fc_w   = (const float*)d_in[5];
    const float* fc_b   = (const float*)d_in[6];
    const int*   tx     = (const int*)d_in[9];
    const int*   ty     = (const int*)d_in[10];

    float* M   = (float*)d_ws;        // 62*62*4 = 15376 bytes
    float* out = (float*)d_out;

    const int B = in_sizes[0] / (NNODE * FIN);   // 4096

    build_M<<<1, 256, 0, stream>>>(ew, tx, ty, M);
    rgnn_fwd<<<B, 256, 0, stream>>>(X, M, lin_w, lin_b, fc_w, fc_b, out);
}